// Round 3
// baseline (398.132 us; speedup 1.0000x reference)
//
#include <hip/hip_runtime.h>
#include <math.h>

#define DFEAT 4096
#define NQ 6
#define ROWS_PER_WAVE 4
#define WAVES_PER_BLOCK 4
#define ROWS_PER_BLOCK (ROWS_PER_WAVE * WAVES_PER_BLOCK)
#define SLAB 256                 // d's (W1 rows) per K-iteration
#define NIT (DFEAT / SLAB)       // 16
#define SLABW (SLAB * NQ)        // 1536 words = 6 KB per slab

typedef float floatx4 __attribute__((ext_vector_type(4)));  // clang-native: ok for nontemporal builtins

// Fused: h = x@W1 + b1; a = h/||h||; 15 RBS (Givens) rotations; z = 1-2a^2
// (NaN->0); out = sigmoid(z@W2 + b2).
//
// W1 slab (6 KB/iter) cooperatively loaded coalesced (float2), staged
// TRANSPOSED in LDS (wl[j][256]) shared by all 4 waves, double-buffered,
// one barrier/iter. Compute-side W1 reads: 6 conflict-free ds_read_b128.
// x streamed nontemporal (no reuse; keep it out of L2's way).
__global__ __launch_bounds__(256, 4)
void hybrid_fused_kernel(const float* __restrict__ x,
                         const float* __restrict__ W1,
                         const float* __restrict__ b1,
                         const float* __restrict__ qw,
                         const float* __restrict__ W2,
                         const float* __restrict__ b2,
                         float* __restrict__ out, int B)
{
    __shared__ float wl[2][NQ * SLAB];   // 2 x 6 KB, transposed: [j*SLAB + d_local]

    const int t = threadIdx.x;
    const int lane = t & 63;
    const int wave = t >> 6;
    int row0 = (blockIdx.x * WAVES_PER_BLOCK + wave) * ROWS_PER_WAVE;
    // No early return (barriers below); clamp rows instead. B=16384 -> exact grid.
    const float* xp[ROWS_PER_WAVE];
#pragma unroll
    for (int r = 0; r < ROWS_PER_WAVE; ++r) {
        int rr = row0 + r; if (rr > B - 1) rr = B - 1;
        xp[r] = x + (size_t)rr * DFEAT;
    }

    // Precompute the 6 transposed LDS word-offsets for this thread's 3 float2s
    // (slab-relative; identical every iteration, only the buffer flips).
    int off[6];
    {
        const int ws[3] = { 2 * t, 2 * (t + 256), 2 * (t + 512) };
#pragma unroll
        for (int p = 0; p < 3; ++p) {
            const int w = ws[p];
            off[2 * p]     = (w % NQ) * SLAB + (w / NQ);
            off[2 * p + 1] = ((w + 1) % NQ) * SLAB + ((w + 1) / NQ);
        }
    }

    float acc[ROWS_PER_WAVE][NQ];
#pragma unroll
    for (int r = 0; r < ROWS_PER_WAVE; ++r)
#pragma unroll
        for (int j = 0; j < NQ; ++j) acc[r][j] = 0.0f;

    // Preload slab 0 into buffer 0.
    {
        const float2* base = reinterpret_cast<const float2*>(W1);
        const float2 p0 = base[t], p1 = base[t + 256], p2 = base[t + 512];
        float* wb = wl[0];
        wb[off[0]] = p0.x; wb[off[1]] = p0.y;
        wb[off[2]] = p1.x; wb[off[3]] = p1.y;
        wb[off[4]] = p2.x; wb[off[5]] = p2.y;
    }
    __syncthreads();

    for (int it = 0; it < NIT; ++it) {
        const int cur = it & 1;
        const int nxt = cur ^ 1;

        // Prefetch next slab into registers (loads in flight during compute).
        float2 q0, q1, q2;
        const bool pf = (it + 1 < NIT);
        if (pf) {
            const float2* base =
                reinterpret_cast<const float2*>(W1 + (size_t)(it + 1) * SLABW);
            q0 = base[t]; q1 = base[t + 256]; q2 = base[t + 512];
        }

        // W1 fragment for this lane: rows d0+lane*4 .. +3, all 6 columns.
        floatx4 wj[NQ];
        const float* wb = wl[cur];
#pragma unroll
        for (int j = 0; j < NQ; ++j)
            wj[j] = *reinterpret_cast<const floatx4*>(&wb[j * SLAB + lane * 4]);

        const int d = it * SLAB + lane * 4;
#pragma unroll
        for (int r = 0; r < ROWS_PER_WAVE; ++r) {
            const floatx4 xv = __builtin_nontemporal_load(
                reinterpret_cast<const floatx4*>(xp[r] + d));
#pragma unroll
            for (int j = 0; j < NQ; ++j) {
                acc[r][j] = fmaf(xv.x, wj[j].x, acc[r][j]);
                acc[r][j] = fmaf(xv.y, wj[j].y, acc[r][j]);
                acc[r][j] = fmaf(xv.z, wj[j].z, acc[r][j]);
                acc[r][j] = fmaf(xv.w, wj[j].w, acc[r][j]);
            }
        }

        if (pf) {
            float* wn = wl[nxt];
            wn[off[0]] = q0.x; wn[off[1]] = q0.y;
            wn[off[2]] = q1.x; wn[off[3]] = q1.y;
            wn[off[4]] = q2.x; wn[off[5]] = q2.y;
        }
        __syncthreads();
    }

    // Wave-wide butterfly reduction: every lane ends with the full sums.
#pragma unroll
    for (int r = 0; r < ROWS_PER_WAVE; ++r)
#pragma unroll
        for (int j = 0; j < NQ; ++j) {
            float v = acc[r][j];
#pragma unroll
            for (int offs = 32; offs >= 1; offs >>= 1)
                v += __shfl_xor(v, offs, 64);
            acc[r][j] = v;
        }

    // Tail: lanes 0..3 each finish one row.
    if (lane < ROWS_PER_WAVE) {
        float h[NQ];
#pragma unroll
        for (int j = 0; j < NQ; ++j) {
            float v = acc[0][j];
            v = (lane == 1) ? acc[1][j] : v;
            v = (lane == 2) ? acc[2][j] : v;
            v = (lane == 3) ? acc[3][j] : v;
            h[j] = v + b1[j];
        }
        float n2 = 0.0f;
#pragma unroll
        for (int j = 0; j < NQ; ++j) n2 = fmaf(h[j], h[j], n2);
        const float inv = rsqrtf(n2);
        float a[NQ];
#pragma unroll
        for (int j = 0; j < NQ; ++j) a[j] = h[j] * inv;

        // pyramid_top_wires(6) = [4,3,2,4,1,3,0,2,4,1,3,2,4,3,4]
        const int topw[15] = {4,3,2,4,1,3,0,2,4,1,3,2,4,3,4};
#pragma unroll
        for (int k = 0; k < 15; ++k) {
            const int q = topw[k];          // constant after unroll
            const float c = cosf(qw[k]);
            const float s = sinf(qw[k]);
            const float aq  = fmaf(c, a[q],     s * a[q + 1]);
            const float aq1 = fmaf(c, a[q + 1], -s * a[q]);
            a[q] = aq;
            a[q + 1] = aq1;
        }

        float zac = b2[0];
#pragma unroll
        for (int j = 0; j < NQ; ++j) {
            float z = 1.0f - 2.0f * a[j] * a[j];
            z = isnan(z) ? 0.0f : z;        // NaN guard from reference
            zac = fmaf(z, W2[j], zac);
        }
        const float o = 1.0f / (1.0f + expf(-zac));
        const int row = row0 + lane;
        if (row < B) out[row] = o;
    }
}

extern "C" void kernel_launch(void* const* d_in, const int* in_sizes, int n_in,
                              void* d_out, int out_size, void* d_ws, size_t ws_size,
                              hipStream_t stream) {
    const float* x  = (const float*)d_in[0];
    const float* W1 = (const float*)d_in[1];
    const float* b1 = (const float*)d_in[2];
    const float* qw = (const float*)d_in[3];
    const float* W2 = (const float*)d_in[4];
    const float* b2 = (const float*)d_in[5];
    float* out = (float*)d_out;

    const int B = in_sizes[0] / DFEAT;                             // 16384
    const int blocks = (B + ROWS_PER_BLOCK - 1) / ROWS_PER_BLOCK;  // 1024
    hybrid_fused_kernel<<<blocks, 256, 0, stream>>>(x, W1, b1, qw, W2, b2, out, B);
}

// Round 4
// 382.672 us; speedup vs baseline: 1.0404x; 1.0404x over previous
//
#include <hip/hip_runtime.h>
#include <math.h>

#define DFEAT 4096
#define NQ 6
#define ROWS_PER_WAVE 4
#define WAVES_PER_BLOCK 4
#define ROWS_PER_BLOCK (ROWS_PER_WAVE * WAVES_PER_BLOCK)
#define SLAB 256                 // W1 rows staged per iteration per wave
#define NIT (DFEAT / SLAB)       // 16
#define COLP 257                 // padded LDS column stride (banks spread)

typedef float floatx4 __attribute__((ext_vector_type(4)));
typedef float floatx2 __attribute__((ext_vector_type(2)));

// Fused: h = x@W1 + b1; a = h/||h||; 15 RBS (Givens) rotations; z = 1-2a^2
// (NaN->0); out = sigmoid(z@W2 + b2).
//
// R4: W1 slab staged per-iteration into WAVE-PRIVATE LDS (6.02 KB/wave,
// transposed, COLP=257 pad). Global W1 loads are coalesced float2 (8 lines
// per instr vs 64 for the old 96B-stride float4s); compute-side reads are 6
// conflict-free ds_read_b128. Private region per wave => ZERO __syncthreads
// (R3's 16 full-drain barriers are gone); ordering is in-order DS + lgkmcnt.
// 24.1 KB LDS/block keeps 4 blocks/CU = 16 waves/CU. No nontemporal flags.
__global__ __launch_bounds__(256, 4)
void hybrid_fused_kernel(const float* __restrict__ x,
                         const float* __restrict__ W1,
                         const float* __restrict__ b1,
                         const float* __restrict__ qw,
                         const float* __restrict__ W2,
                         const float* __restrict__ b2,
                         float* __restrict__ out, int B)
{
    __shared__ float wl_all[WAVES_PER_BLOCK][NQ * COLP];

    const int t = threadIdx.x;
    const int lane = t & 63;
    const int wave = t >> 6;
    float* __restrict__ wl = wl_all[wave];     // this wave's private region

    const int row0 = (blockIdx.x * WAVES_PER_BLOCK + wave) * ROWS_PER_WAVE;
    if (row0 >= B) return;                     // no barriers => safe

    const float* xp[ROWS_PER_WAVE];
#pragma unroll
    for (int r = 0; r < ROWS_PER_WAVE; ++r) {
        int rr = row0 + r; if (rr > B - 1) rr = B - 1;
        xp[r] = x + (size_t)rr * DFEAT;
    }

    // Transposed scatter offsets. Word w (0..1535) of a slab goes to
    // wl[(w%6)*COLP + w/6]. Thread handles float2 p at w=2*(p*64+lane);
    // offsets for p and p+3 differ by exactly +64 (128*3 % 6 == 0), so only
    // p%3 = 0,1,2 need computing (6 registers).
    int offe[3], offo[3];
#pragma unroll
    for (int p3 = 0; p3 < 3; ++p3) {
        const int we = 128 * p3 + 2 * lane;
        const int wo = we + 1;
        offe[p3] = (we % 6) * COLP + we / 6;
        offo[p3] = (wo % 6) * COLP + wo / 6;
    }

    float acc[ROWS_PER_WAVE][NQ];
#pragma unroll
    for (int r = 0; r < ROWS_PER_WAVE; ++r)
#pragma unroll
        for (int j = 0; j < NQ; ++j) acc[r][j] = 0.0f;

    // 1-deep x prefetch.
    floatx4 xv[ROWS_PER_WAVE];
#pragma unroll
    for (int r = 0; r < ROWS_PER_WAVE; ++r)
        xv[r] = *reinterpret_cast<const floatx4*>(xp[r] + lane * 4);

    for (int it = 0; it < NIT; ++it) {
        // Stage this iteration's W1 slab: 12 coalesced float2 loads/lane.
        floatx2 wv[12];
        const floatx2* wbase =
            reinterpret_cast<const floatx2*>(W1 + (size_t)it * SLAB * NQ);
#pragma unroll
        for (int p = 0; p < 12; ++p)
            wv[p] = wbase[p * 64 + lane];

#pragma unroll
        for (int p = 0; p < 12; ++p) {
            const int add = 64 * (p / 3);      // compile-time per unrolled p
            wl[offe[p % 3] + add] = wv[p].x;
            wl[offo[p % 3] + add] = wv[p].y;
        }

        // This lane's W1 fragment: rows it*256+lane*4 .. +3, all 6 columns.
        floatx4 wj[NQ];
#pragma unroll
        for (int j = 0; j < NQ; ++j)
            wj[j] = *reinterpret_cast<const floatx4*>(&wl[j * COLP + lane * 4]);

        // Prefetch next iteration's x while FMAs run.
        floatx4 xn[ROWS_PER_WAVE];
        if (it + 1 < NIT) {
            const int d = (it + 1) * SLAB + lane * 4;
#pragma unroll
            for (int r = 0; r < ROWS_PER_WAVE; ++r)
                xn[r] = *reinterpret_cast<const floatx4*>(xp[r] + d);
        }

#pragma unroll
        for (int r = 0; r < ROWS_PER_WAVE; ++r) {
#pragma unroll
            for (int j = 0; j < NQ; ++j) {
                acc[r][j] = fmaf(xv[r].x, wj[j].x, acc[r][j]);
                acc[r][j] = fmaf(xv[r].y, wj[j].y, acc[r][j]);
                acc[r][j] = fmaf(xv[r].z, wj[j].z, acc[r][j]);
                acc[r][j] = fmaf(xv[r].w, wj[j].w, acc[r][j]);
            }
        }
#pragma unroll
        for (int r = 0; r < ROWS_PER_WAVE; ++r) xv[r] = xn[r];
    }

    // Wave-wide butterfly reduction: every lane ends with the full sums.
#pragma unroll
    for (int r = 0; r < ROWS_PER_WAVE; ++r)
#pragma unroll
        for (int j = 0; j < NQ; ++j) {
            float v = acc[r][j];
#pragma unroll
            for (int offs = 32; offs >= 1; offs >>= 1)
                v += __shfl_xor(v, offs, 64);
            acc[r][j] = v;
        }

    // Tail: lanes 0..3 each finish one row.
    if (lane < ROWS_PER_WAVE) {
        float h[NQ];
#pragma unroll
        for (int j = 0; j < NQ; ++j) {
            float v = acc[0][j];
            v = (lane == 1) ? acc[1][j] : v;
            v = (lane == 2) ? acc[2][j] : v;
            v = (lane == 3) ? acc[3][j] : v;
            h[j] = v + b1[j];
        }
        float n2 = 0.0f;
#pragma unroll
        for (int j = 0; j < NQ; ++j) n2 = fmaf(h[j], h[j], n2);
        const float inv = rsqrtf(n2);
        float a[NQ];
#pragma unroll
        for (int j = 0; j < NQ; ++j) a[j] = h[j] * inv;

        // pyramid_top_wires(6) = [4,3,2,4,1,3,0,2,4,1,3,2,4,3,4]
        const int topw[15] = {4,3,2,4,1,3,0,2,4,1,3,2,4,3,4};
#pragma unroll
        for (int k = 0; k < 15; ++k) {
            const int q = topw[k];          // constant after unroll
            const float c = cosf(qw[k]);
            const float s = sinf(qw[k]);
            const float aq  = fmaf(c, a[q],     s * a[q + 1]);
            const float aq1 = fmaf(c, a[q + 1], -s * a[q]);
            a[q] = aq;
            a[q + 1] = aq1;
        }

        float zac = b2[0];
#pragma unroll
        for (int j = 0; j < NQ; ++j) {
            float z = 1.0f - 2.0f * a[j] * a[j];
            z = isnan(z) ? 0.0f : z;        // NaN guard from reference
            zac = fmaf(z, W2[j], zac);
        }
        const float o = 1.0f / (1.0f + expf(-zac));
        const int row = row0 + lane;
        if (row < B) out[row] = o;
    }
}

extern "C" void kernel_launch(void* const* d_in, const int* in_sizes, int n_in,
                              void* d_out, int out_size, void* d_ws, size_t ws_size,
                              hipStream_t stream) {
    const float* x  = (const float*)d_in[0];
    const float* W1 = (const float*)d_in[1];
    const float* b1 = (const float*)d_in[2];
    const float* qw = (const float*)d_in[3];
    const float* W2 = (const float*)d_in[4];
    const float* b2 = (const float*)d_in[5];
    float* out = (float*)d_out;

    const int B = in_sizes[0] / DFEAT;                             // 16384
    const int blocks = (B + ROWS_PER_BLOCK - 1) / ROWS_PER_BLOCK;  // 1024
    hybrid_fused_kernel<<<blocks, 256, 0, stream>>>(x, W1, b1, qw, W2, b2, out, B);
}

// Round 5
// 380.051 us; speedup vs baseline: 1.0476x; 1.0069x over previous
//
#include <hip/hip_runtime.h>
#include <math.h>

#define DFEAT 4096
#define NQ 6
#define ROWS_PER_WAVE 4
#define WAVES_PER_BLOCK 4
#define ROWS_PER_BLOCK (ROWS_PER_WAVE * WAVES_PER_BLOCK)
#define SLAB 256                 // k-elements per wave-iteration (64 lanes x float4)
#define NIT (DFEAT / SLAB)       // 16

typedef float floatx4 __attribute__((ext_vector_type(4)));

// Fused: h = x@W1 + b1; a = h/||h||; 15 RBS (Givens) rotations; z = 1-2a^2
// (NaN->0); out = sigmoid(z@W2 + b2).
//
// R5: no LDS (R1==R4 proved the W1 path is off the critical path; slab is
// L1-hot). Both x and W1 are software-pipelined 2 deep with 2-buffer
// rotation: loads for it+2 issue right after buffer (it&1) is consumed, so
// each iteration's FMAs wait on loads issued two iterations earlier
// (~8 KB x in flight per wave, ~128 KB/CU). No barriers anywhere.
// __launch_bounds__(256,4) caps VGPR at 128 -> 16 waves/CU resident.
__global__ __launch_bounds__(256, 4)
void hybrid_fused_kernel(const float* __restrict__ x,
                         const float* __restrict__ W1,
                         const float* __restrict__ b1,
                         const float* __restrict__ qw,
                         const float* __restrict__ W2,
                         const float* __restrict__ b2,
                         float* __restrict__ out, int B)
{
    const int t = threadIdx.x;
    const int lane = t & 63;
    const int wave = t >> 6;
    const int row0 = (blockIdx.x * WAVES_PER_BLOCK + wave) * ROWS_PER_WAVE;
    if (row0 >= B) return;

    const float* xp[ROWS_PER_WAVE];
#pragma unroll
    for (int r = 0; r < ROWS_PER_WAVE; ++r) {
        int rr = row0 + r; if (rr > B - 1) rr = B - 1;
        xp[r] = x + (size_t)rr * DFEAT;
    }
    // W1 fragment base for this lane: rows (it*256 + lane*4)..+3, 6 cols each
    // = 24 contiguous floats = 6 float4s (96 B, 16B-aligned).
    const floatx4* wfrag0 =
        reinterpret_cast<const floatx4*>(W1 + (size_t)lane * 4 * NQ);

    float acc[ROWS_PER_WAVE][NQ];
#pragma unroll
    for (int r = 0; r < ROWS_PER_WAVE; ++r)
#pragma unroll
        for (int j = 0; j < NQ; ++j) acc[r][j] = 0.0f;

    // Double-buffered pipeline registers: x (4 rows x float4) and W1 (6 float4).
    floatx4 xb[2][ROWS_PER_WAVE];
    floatx4 wb[2][NQ];

    // Prologue: fill both buffers (iterations 0 and 1).
#pragma unroll
    for (int p = 0; p < 2; ++p) {
        const int d = p * SLAB + lane * 4;
#pragma unroll
        for (int r = 0; r < ROWS_PER_WAVE; ++r)
            xb[p][r] = *reinterpret_cast<const floatx4*>(xp[r] + d);
        const floatx4* wf = wfrag0 + (size_t)p * SLAB * NQ / 4;
#pragma unroll
        for (int j = 0; j < NQ; ++j)
            wb[p][j] = wf[j];
    }

    for (int it = 0; it < NIT; ++it) {
        const int cur = it & 1;

        // Consume buffer `cur` (loads were issued 2 iterations ago).
        // wb[cur][j] holds W1 rows d..d+3 in row-major 4x6; transpose inline:
        // w[k][j] = wb[cur][(4k+j)/4][(4k+j)%4]  -- done via component refs.
        const floatx4 w0 = wb[cur][0], w1 = wb[cur][1], w2 = wb[cur][2];
        const floatx4 w3 = wb[cur][3], w4 = wb[cur][4], w5 = wb[cur][5];
        // Row k of W1 fragment (6 floats each):
        // k=0: w0.x w0.y w0.z w0.w w1.x w1.y
        // k=1: w1.z w1.w w2.x w2.y w2.z w2.w
        // k=2: w3.x w3.y w3.z w3.w w4.x w4.y
        // k=3: w4.z w4.w w5.x w5.y w5.z w5.w
#pragma unroll
        for (int r = 0; r < ROWS_PER_WAVE; ++r) {
            const floatx4 xv = xb[cur][r];
            float* A = acc[r];
            A[0] = fmaf(xv.x, w0.x, A[0]); A[1] = fmaf(xv.x, w0.y, A[1]);
            A[2] = fmaf(xv.x, w0.z, A[2]); A[3] = fmaf(xv.x, w0.w, A[3]);
            A[4] = fmaf(xv.x, w1.x, A[4]); A[5] = fmaf(xv.x, w1.y, A[5]);

            A[0] = fmaf(xv.y, w1.z, A[0]); A[1] = fmaf(xv.y, w1.w, A[1]);
            A[2] = fmaf(xv.y, w2.x, A[2]); A[3] = fmaf(xv.y, w2.y, A[3]);
            A[4] = fmaf(xv.y, w2.z, A[4]); A[5] = fmaf(xv.y, w2.w, A[5]);

            A[0] = fmaf(xv.z, w3.x, A[0]); A[1] = fmaf(xv.z, w3.y, A[1]);
            A[2] = fmaf(xv.z, w3.z, A[2]); A[3] = fmaf(xv.z, w3.w, A[3]);
            A[4] = fmaf(xv.z, w4.x, A[4]); A[5] = fmaf(xv.z, w4.y, A[5]);

            A[0] = fmaf(xv.w, w4.z, A[0]); A[1] = fmaf(xv.w, w4.w, A[1]);
            A[2] = fmaf(xv.w, w5.x, A[2]); A[3] = fmaf(xv.w, w5.y, A[3]);
            A[4] = fmaf(xv.w, w5.z, A[4]); A[5] = fmaf(xv.w, w5.w, A[5]);
        }

        // Refill buffer `cur` for iteration it+2 (in flight across it+1).
        if (it + 2 < NIT) {
            const int d = (it + 2) * SLAB + lane * 4;
#pragma unroll
            for (int r = 0; r < ROWS_PER_WAVE; ++r)
                xb[cur][r] = *reinterpret_cast<const floatx4*>(xp[r] + d);
            const floatx4* wf = wfrag0 + (size_t)(it + 2) * SLAB * NQ / 4;
#pragma unroll
            for (int j = 0; j < NQ; ++j)
                wb[cur][j] = wf[j];
        }
    }

    // Wave-wide butterfly reduction: every lane ends with the full sums.
#pragma unroll
    for (int r = 0; r < ROWS_PER_WAVE; ++r)
#pragma unroll
        for (int j = 0; j < NQ; ++j) {
            float v = acc[r][j];
#pragma unroll
            for (int offs = 32; offs >= 1; offs >>= 1)
                v += __shfl_xor(v, offs, 64);
            acc[r][j] = v;
        }

    // Tail: lanes 0..3 each finish one row.
    if (lane < ROWS_PER_WAVE) {
        float h[NQ];
#pragma unroll
        for (int j = 0; j < NQ; ++j) {
            float v = acc[0][j];
            v = (lane == 1) ? acc[1][j] : v;
            v = (lane == 2) ? acc[2][j] : v;
            v = (lane == 3) ? acc[3][j] : v;
            h[j] = v + b1[j];
        }
        float n2 = 0.0f;
#pragma unroll
        for (int j = 0; j < NQ; ++j) n2 = fmaf(h[j], h[j], n2);
        const float inv = rsqrtf(n2);
        float a[NQ];
#pragma unroll
        for (int j = 0; j < NQ; ++j) a[j] = h[j] * inv;

        // pyramid_top_wires(6) = [4,3,2,4,1,3,0,2,4,1,3,2,4,3,4]
        const int topw[15] = {4,3,2,4,1,3,0,2,4,1,3,2,4,3,4};
#pragma unroll
        for (int k = 0; k < 15; ++k) {
            const int q = topw[k];          // constant after unroll
            const float c = cosf(qw[k]);
            const float s = sinf(qw[k]);
            const float aq  = fmaf(c, a[q],     s * a[q + 1]);
            const float aq1 = fmaf(c, a[q + 1], -s * a[q]);
            a[q] = aq;
            a[q + 1] = aq1;
        }

        float zac = b2[0];
#pragma unroll
        for (int j = 0; j < NQ; ++j) {
            float z = 1.0f - 2.0f * a[j] * a[j];
            z = isnan(z) ? 0.0f : z;        // NaN guard from reference
            zac = fmaf(z, W2[j], zac);
        }
        const float o = 1.0f / (1.0f + expf(-zac));
        const int row = row0 + lane;
        if (row < B) out[row] = o;
    }
}

extern "C" void kernel_launch(void* const* d_in, const int* in_sizes, int n_in,
                              void* d_out, int out_size, void* d_ws, size_t ws_size,
                              hipStream_t stream) {
    const float* x  = (const float*)d_in[0];
    const float* W1 = (const float*)d_in[1];
    const float* b1 = (const float*)d_in[2];
    const float* qw = (const float*)d_in[3];
    const float* W2 = (const float*)d_in[4];
    const float* b2 = (const float*)d_in[5];
    float* out = (float*)d_out;

    const int B = in_sizes[0] / DFEAT;                             // 16384
    const int blocks = (B + ROWS_PER_BLOCK - 1) / ROWS_PER_BLOCK;  // 1024
    hybrid_fused_kernel<<<blocks, 256, 0, stream>>>(x, W1, b1, qw, W2, b2, out, B);
}